// Round 7
// baseline (561.083 us; speedup 1.0000x reference)
//
#include <hip/hip_runtime.h>
#include <math.h>

#define IN_DIM  8192
#define OUT_DIM 8192
#define BATCH   8192
#define ROWS    16     // batch rows per block
#define T       1024   // threads per block

// Direct global->LDS DMA, 16B per lane. LDS dest is wave-uniform base
// (HW writes lane i at base + i*16); global src is per-lane.
#define GLOAD_LDS16(g, l) __builtin_amdgcn_global_load_lds( \
    (const __attribute__((address_space(1))) void*)(g),     \
    (__attribute__((address_space(3))) void*)(l), 16, 0, 0)

// GATE_COEFFS rows (c0,c1,c2,c3) per i — folded into hardcoded sums below:
// g0 = e8+..+e15
// g1 = e2+e3+e6+e7 - e8-e9-e12-e13
// g2 = e4+e5+e6+e7 - e8-e9-e10-e11
// g3 = e1-e2-e4-2e6-e7+e8+2e9+e11+e13-e14

// Compute c = softmax(weight_row) @ GATE_COEFFS for one row (16 floats at wr).
__device__ __forceinline__ float4 softmax_gate(const float* wr)
{
    const float4* w4 = (const float4*)wr;
    float e[16];
#pragma unroll
    for (int k = 0; k < 4; ++k) {
        float4 w = w4[k];
        e[4*k+0] = __expf(w.x);
        e[4*k+1] = __expf(w.y);
        e[4*k+2] = __expf(w.z);
        e[4*k+3] = __expf(w.w);
    }
    float s = 0.f;
#pragma unroll
    for (int i = 0; i < 16; ++i) s += e[i];
    float g0 = e[8]+e[9]+e[10]+e[11]+e[12]+e[13]+e[14]+e[15];
    float g1 = e[2]+e[3]+e[6]+e[7] - e[8]-e[9]-e[12]-e[13];
    float g2 = e[4]+e[5]+e[6]+e[7] - e[8]-e[9]-e[10]-e[11];
    float g3 = e[1]-e[2]-e[4]-2.f*e[6]-e[7]+e[8]+2.f*e[9]+e[11]+e[13]-e[14];
    float inv = 1.0f / s;
    return make_float4(g0*inv, g1*inv, g2*inv, g3*inv);
}

// Single fused kernel: persistent block over 16 rows, 2 blocks/CU.
// Prologue: each thread computes softmax@GATE_COEFFS for its own 8 output
// rows directly from weight (no separate kernel, no workspace, no dependency
// bubble). Inner loop identical to R6: DMA-staged double-buffered x row,
// packed u16 byte-offset gathers, counted vmcnt(2) + raw barrier.
__global__ __launch_bounds__(T, 8) void gate_main_kernel(
    const float* __restrict__ x,
    const float* __restrict__ weight,
    const int4* __restrict__ ia4,
    const int4* __restrict__ ib4,
    float4* __restrict__ out)
{
    __shared__ float buf[2][IN_DIM];          // 64 KB
    const int tid  = threadIdx.x;
    const int wave = tid >> 6;
    const size_t r0 = (size_t)blockIdx.x * ROWS;

    // Issue row-0 staging FIRST so its latency hides under the prologue math.
    {
        const float* src = x + r0 * IN_DIM;
        GLOAD_LDS16(src + (tid << 2),        &buf[0][wave << 8]);
        GLOAD_LDS16(src + 4096 + (tid << 2), &buf[0][4096 + (wave << 8)]);
    }

    // Persistent state: 8 packed-offset VGPRs + 32 coeff VGPRs.
    const int q0 = tid, q1 = tid + T;
    unsigned pkA0, pkA1, pkA2, pkA3, pkB0, pkB1, pkB2, pkB3;
    {
        int4 ia = ia4[q0], ib = ib4[q0];
        pkA0 = (unsigned)(ia.x << 2) | ((unsigned)(ib.x << 2) << 16);
        pkA1 = (unsigned)(ia.y << 2) | ((unsigned)(ib.y << 2) << 16);
        pkA2 = (unsigned)(ia.z << 2) | ((unsigned)(ib.z << 2) << 16);
        pkA3 = (unsigned)(ia.w << 2) | ((unsigned)(ib.w << 2) << 16);
        ia = ia4[q1]; ib = ib4[q1];
        pkB0 = (unsigned)(ia.x << 2) | ((unsigned)(ib.x << 2) << 16);
        pkB1 = (unsigned)(ia.y << 2) | ((unsigned)(ib.y << 2) << 16);
        pkB2 = (unsigned)(ia.z << 2) | ((unsigned)(ib.z << 2) << 16);
        pkB3 = (unsigned)(ia.w << 2) | ((unsigned)(ib.w << 2) << 16);
    }

    // Fused coefficient computation: 8 softmax rows per thread.
    const float4 cA0 = softmax_gate(weight + (size_t)(4*q0+0) * 16);
    const float4 cA1 = softmax_gate(weight + (size_t)(4*q0+1) * 16);
    const float4 cA2 = softmax_gate(weight + (size_t)(4*q0+2) * 16);
    const float4 cA3 = softmax_gate(weight + (size_t)(4*q0+3) * 16);
    const float4 cB0 = softmax_gate(weight + (size_t)(4*q1+0) * 16);
    const float4 cB1 = softmax_gate(weight + (size_t)(4*q1+1) * 16);
    const float4 cB2 = softmax_gate(weight + (size_t)(4*q1+2) * 16);
    const float4 cB3 = softmax_gate(weight + (size_t)(4*q1+3) * 16);

    asm volatile("s_waitcnt vmcnt(0)" ::: "memory");
    __builtin_amdgcn_s_barrier();

    for (int r = 0; r < ROWS; ++r) {
        const int cur = r & 1;

        // (1) issue next-row DMA into the other buffer.
        if (r + 1 < ROWS) {
            const float* src = x + (r0 + r + 1) * IN_DIM;
            float* bn = buf[cur ^ 1];
            GLOAD_LDS16(src + (tid << 2),        bn + (wave << 8));
            GLOAD_LDS16(src + 4096 + (tid << 2), bn + 4096 + (wave << 8));
        }
        asm volatile("" ::: "memory");   // pin DMA issue before the stores below

        // (2) gather + compute + store current row
        const char* xb = (const char*)buf[cur];
        float4* orow = out + (r0 + r) * (OUT_DIM / 4);
        {
            float a0 = *(const float*)(xb + (pkA0 & 0xffffu));
            float b0 = *(const float*)(xb + (pkA0 >> 16));
            float a1 = *(const float*)(xb + (pkA1 & 0xffffu));
            float b1 = *(const float*)(xb + (pkA1 >> 16));
            float a2 = *(const float*)(xb + (pkA2 & 0xffffu));
            float b2 = *(const float*)(xb + (pkA2 >> 16));
            float a3 = *(const float*)(xb + (pkA3 & 0xffffu));
            float b3 = *(const float*)(xb + (pkA3 >> 16));
            float4 o;
            o.x = fmaf(a0, fmaf(b0, cA0.w, cA0.y), fmaf(b0, cA0.z, cA0.x));
            o.y = fmaf(a1, fmaf(b1, cA1.w, cA1.y), fmaf(b1, cA1.z, cA1.x));
            o.z = fmaf(a2, fmaf(b2, cA2.w, cA2.y), fmaf(b2, cA2.z, cA2.x));
            o.w = fmaf(a3, fmaf(b3, cA3.w, cA3.y), fmaf(b3, cA3.z, cA3.x));
            orow[q0] = o;
        }
        {
            float a0 = *(const float*)(xb + (pkB0 & 0xffffu));
            float b0 = *(const float*)(xb + (pkB0 >> 16));
            float a1 = *(const float*)(xb + (pkB1 & 0xffffu));
            float b1 = *(const float*)(xb + (pkB1 >> 16));
            float a2 = *(const float*)(xb + (pkB2 & 0xffffu));
            float b2 = *(const float*)(xb + (pkB2 >> 16));
            float a3 = *(const float*)(xb + (pkB3 & 0xffffu));
            float b3 = *(const float*)(xb + (pkB3 >> 16));
            float4 o;
            o.x = fmaf(a0, fmaf(b0, cB0.w, cB0.y), fmaf(b0, cB0.z, cB0.x));
            o.y = fmaf(a1, fmaf(b1, cB1.w, cB1.y), fmaf(b1, cB1.z, cB1.x));
            o.z = fmaf(a2, fmaf(b2, cB2.w, cB2.y), fmaf(b2, cB2.z, cB2.x));
            o.w = fmaf(a3, fmaf(b3, cB3.w, cB3.y), fmaf(b3, cB3.z, cB3.x));
            orow[q1] = o;
        }

        // (3) counted wait: guarantees this row's 2 staging DMAs landed in
        // LDS; our own 2 output stores may still be in flight (nobody reads).
        if (r + 1 < ROWS) {
            asm volatile("s_waitcnt vmcnt(2)" ::: "memory");
            __builtin_amdgcn_s_barrier();
        }
    }
}

extern "C" void kernel_launch(void* const* d_in, const int* in_sizes, int n_in,
                              void* d_out, int out_size, void* d_ws, size_t ws_size,
                              hipStream_t stream) {
    const float* x      = (const float*)d_in[0];
    const float* weight = (const float*)d_in[1];
    const int*   idx_a  = (const int*)d_in[2];
    const int*   idx_b  = (const int*)d_in[3];
    float* out = (float*)d_out;

    gate_main_kernel<<<BATCH / ROWS, T, 0, stream>>>(
        x, weight, (const int4*)idx_a, (const int4*)idx_b, (float4*)out);
}